// Round 16
// baseline (241.338 us; speedup 1.0000x reference)
//
#include <hip/hip_runtime.h>
#include <hip/hip_bf16.h>

// ---------------------------------------------------------------------------
// PAWSA fused windowed attention, MI355X / gfx950 — round 16: swapped-operand
// attention. Inputs f32, output f32 (out0 [8192,49,96], out1 v_hw [8,3,96] at
// elem offset 38,535,168). One block/window (8192 x 256), bf16 MFMA 16x16x32.
// vs R15:
//   - QK^T computed swapped: S^T = mfma(A=K,B=Q) -> lane holds S[key][q=W+lr]
//     (16 keys for ONE query). Same LDS reads; only operand order changes.
//   - softmax fully in-lane (15 fmax + 2 shfl) — shorter serial chain.
//   - P stays in REGISTERS: PV B-frag built via 8x ds_bpermute + 4 selects.
//     PV computes O^T (A=VT, same reads as before), accumulated in regs.
//   - O stays in registers; same bpermute transpose feeds projection A-frag.
//   - LDS: XQ[49][98] + K[52][100] + VT[96][66] = 32,676 B -> 5 blocks/CU.
//   - ONE barrier per block (proj reads nothing from LDS).
// Garbage map: keys>=52 -> logit -1e30 -> exp=0 exact; q>=49 columns NaN-able
// but lane-confined (bpermute/shfl stay within same lr=q) and store-masked.
// ---------------------------------------------------------------------------

typedef __bf16 bf16x8 __attribute__((ext_vector_type(8)));
typedef float  f32x4  __attribute__((ext_vector_type(4)));
typedef short  s16x4  __attribute__((ext_vector_type(4)));
typedef unsigned short u16x4 __attribute__((ext_vector_type(4)));
typedef int    i32x4  __attribute__((ext_vector_type(4)));
using bf16 = __hip_bfloat16;

#define SCALE 0.17677669529663687f   // 32^-0.5

// LDS partition (units: 16-bit elements) — 16,338 shorts = 32,676 B
#define LDS_XQ    0       // [49][98]  q (rows<49)
#define LDS_K     4802    // [52][100] k
#define LDS_VT    10002   // [96][66]  v^T: vt[h*32+d][token]
#define LDS_TOT   16338

static __device__ inline float s2f(unsigned short s) {
    unsigned int u = ((unsigned int)s) << 16;
    float f;
    __builtin_memcpy(&f, &u, 4);
    return f;
}
static __device__ inline short f2s(float f) {   // hardware cvt
    __bf16 h = (__bf16)f;
    short s;
    __builtin_memcpy(&s, &h, 2);
    return s;
}
static __device__ inline int pk2(float a, float b) {  // pack 2 f32 -> bf16x2
    unsigned int lo = (unsigned short)f2s(a);
    unsigned int hi = (unsigned short)f2s(b);
    return (int)(lo | (hi << 16));
}
static __device__ inline bf16x8 ldw8(const float* p) {   // f32 -> bf16 fragment
    f32x4 a = *reinterpret_cast<const f32x4*>(p);
    f32x4 b = *reinterpret_cast<const f32x4*>(p + 4);
    bf16x8 r;
    #pragma unroll
    for (int i = 0; i < 4; ++i) {
        r[i]     = (__bf16)a[i];
        r[i + 4] = (__bf16)b[i];
    }
    return r;
}
// Build A/B-frag [q=lr][k=32ks+8lg+t] from lane-held tiles: candidates
// c0*={reg 2ks}, c1*={reg 2ks+1}; src lanes iA (t<4), iB (t>=4); sel by lg>=2.
static __device__ inline bf16x8 xfrag(int c00, int c01, int c10, int c11,
                                      int iA, int iB, int selHi) {
    int a0 = __builtin_amdgcn_ds_bpermute(iA, c00);
    int a1 = __builtin_amdgcn_ds_bpermute(iA, c10);
    int h0 = __builtin_amdgcn_ds_bpermute(iA, c01);
    int h1 = __builtin_amdgcn_ds_bpermute(iA, c11);
    int b0 = __builtin_amdgcn_ds_bpermute(iB, c00);
    int b1 = __builtin_amdgcn_ds_bpermute(iB, c10);
    int g0 = __builtin_amdgcn_ds_bpermute(iB, c01);
    int g1 = __builtin_amdgcn_ds_bpermute(iB, c11);
    i32x4 r;
    r[0] = selHi ? a1 : a0;
    r[1] = selHi ? h1 : h0;
    r[2] = selHi ? b1 : b0;
    r[3] = selHi ? g1 : g0;
    return __builtin_bit_cast(bf16x8, r);
}

// ---- prep: bf16 weights (blocks 0-143) + gathered bias table (block 144) ----
// ws layout (bf16 elems): [0,27648) qkv_w | [27648,36864) proj_w |
//                         [36864, +12288) biasg as ushort4[12][256]
__global__ __launch_bounds__(256)
void pawsa_prep(const float* __restrict__ qkv_w, const float* __restrict__ proj_w,
                const float* __restrict__ bias_table, bf16* __restrict__ ws)
{
    int blk = blockIdx.x, t = threadIdx.x;
    if (blk < 144) {
        int i = blk * 256 + t;
        if (i < 27648)      ws[i] = __float2bfloat16(qkv_w[i]);
        else if (i < 36864) ws[i] = __float2bfloat16(proj_w[i - 27648]);
        return;
    }
    // swapped layout: biasg[(h*4+nt)*256+tid] = {bias[idx(q, key=16nt+4lg+j)][h]}
    int lane = t & 63, wid = t >> 6;
    int lr = lane & 15, lg = lane >> 4;
    int q = wid * 16 + lr;
    u16x4* bg = reinterpret_cast<u16x4*>(ws + 36864);
    for (int h = 0; h < 3; ++h) {
        for (int nt = 0; nt < 4; ++nt) {
            u16x4 v4;
            for (int j = 0; j < 4; ++j) {
                int key = nt * 16 + lg * 4 + j;
                int idx = 171;
                if (key < 49) {
                    if (q < 49)
                        idx = (q / 7 - key / 7 + 6) * 13 + (q % 7 - key % 7 + 6);
                } else if (key < 52) {
                    idx = 169 + (key - 49);
                }
                v4[j] = (unsigned short)f2s(bias_table[idx * 3 + h]);
            }
            bg[(h * 4 + nt) * 256 + t] = v4;
        }
    }
}

__global__ __launch_bounds__(256, 4)
void pawsa_main(const float* __restrict__ x, const float* __restrict__ mask,
                const float* __restrict__ uk, const float* __restrict__ fg,
                const float* __restrict__ bg,
                const bf16* __restrict__ wq,    // bf16 qkv_w (d_ws)
                const float* __restrict__ qkv_b,
                const bf16* __restrict__ wp,    // bf16 proj_w (d_ws)
                const float* __restrict__ proj_b,
                const u16x4* __restrict__ biasg, // gathered bias (d_ws)
                float* __restrict__ out)
{
    __shared__ short smem[LDS_TOT];

    const int tid  = threadIdx.x;
    const int w    = blockIdx.x;       // window id
    const int b    = w >> 10;          // batch (nW = 1024)
    const int wi   = w & 1023;         // window-in-batch
    const int lane = tid & 63;
    const int wid  = tid >> 6;         // wave id 0..3
    const int lr   = lane & 15;        // row/col within 16-tile
    const int lg   = lane >> 4;        // k-group 0..3
    const int q    = wid * 16 + lr;    // this lane's query row (swapped layout)

    // bpermute source-lane indices (byte units); depend only on lg&1
    const int iA = (lr + ((lg & 1) << 5)) << 2;        // lane lr + 32*(lg&1)
    const int iB = (lr + ((lg & 1) << 5) + 16) << 2;
    const int selHi = (lg >= 2);

    // ---- X tile -> registers directly (rows<49 x, 49-51 priors, >=52 zero) --
    bf16x8 af[3][4];
    #pragma unroll
    for (int mt = 0; mt < 4; ++mt) {
        int n = mt * 16 + lr;
        #pragma unroll
        for (int ks = 0; ks < 3; ++ks) {
            bf16x8 a = (bf16x8)0;
            if (n < 49) {
                a = ldw8(x + ((size_t)w * 49 + n) * 96 + ks * 32 + lg * 8);
            } else if (n < 52) {
                const float* pr = (n == 49) ? uk : (n == 50) ? fg : bg;
                a = ldw8(pr + b * 96 + ks * 32 + lg * 8);
            }
            af[ks][mt] = a;
        }
    }

    // ---- QKV GEMM: wave-split tiles (0-4,5-9,10-14,13-17; 13,14 dup benign) --
    const int nt0 = (wid < 3) ? wid * 5 : 13;
    #pragma unroll
    for (int i = 0; i < 5; ++i) {
        int o = (nt0 + i) * 16 + lr;          // output channel 0..287
        bf16x8 bw0 = *reinterpret_cast<const bf16x8*>(wq + o * 96 +  0 + lg * 8);
        bf16x8 bw1 = *reinterpret_cast<const bf16x8*>(wq + o * 96 + 32 + lg * 8);
        bf16x8 bw2 = *reinterpret_cast<const bf16x8*>(wq + o * 96 + 64 + lg * 8);
        float  qb  = qkv_b[o];
        f32x4 acc[4] = {(f32x4)0.f, (f32x4)0.f, (f32x4)0.f, (f32x4)0.f};
        #pragma unroll
        for (int mt = 0; mt < 4; ++mt) {
            acc[mt] = __builtin_amdgcn_mfma_f32_16x16x32_bf16(af[0][mt], bw0, acc[mt], 0, 0, 0);
            acc[mt] = __builtin_amdgcn_mfma_f32_16x16x32_bf16(af[1][mt], bw1, acc[mt], 0, 0, 0);
            acc[mt] = __builtin_amdgcn_mfma_f32_16x16x32_bf16(af[2][mt], bw2, acc[mt], 0, 0, 0);
        }
        int s = o / 96;                       // 0=q 1=k 2=v
        int rem = o - s * 96;
        #pragma unroll
        for (int mt = 0; mt < 4; ++mt) {
            if (s == 2) {                     // v: 4 consecutive tokens -> b64
                s16x4 pk;
                #pragma unroll
                for (int j = 0; j < 4; ++j) pk[j] = f2s(acc[mt][j] + qb);
                *reinterpret_cast<s16x4*>(
                    &smem[LDS_VT + rem * 66 + mt * 16 + lg * 4]) = pk;
            } else {
                #pragma unroll
                for (int j = 0; j < 4; ++j) {
                    int n = mt * 16 + lg * 4 + j;
                    short hv = f2s(acc[mt][j] + qb);
                    if (s == 0) { if (n < 49) smem[LDS_XQ + n * 98  + rem] = hv; }
                    else        { if (n < 52) smem[LDS_K  + n * 100 + rem] = hv; }
                }
            }
        }
    }

    // ---- mask loads, swapped layout: mk[nt][j] = mask[q][key=16nt+4lg+j] ----
    float mk[4][4];
    #pragma unroll
    for (int nt = 0; nt < 4; ++nt) {
        #pragma unroll
        for (int j = 0; j < 4; ++j) {
            int key = nt * 16 + lg * 4 + j;
            float m = 0.f;
            if (q < 49 && key < 49)
                m = mask[(size_t)wi * 2401 + q * 49 + key];
            mk[nt][j] = m;
        }
    }

    __syncthreads();
    // From here all LDS is read-only. ONE barrier per block.

    // ---- per-head attention: S^T via swapped mfma; O^T accumulated in regs --
    f32x4 oacc[6];   // O^T tiles: T=h*2+a -> O^T[h*32+a*16+lg*4+j][q]
    #pragma unroll
    for (int T = 0; T < 6; ++T) oacc[T] = (f32x4)0.f;

    #pragma unroll
    for (int h = 0; h < 3; ++h) {
        // bias (gathered, swapped layout): 4 x 8B loads, L2-hot
        u16x4 bgq[4];
        #pragma unroll
        for (int nt = 0; nt < 4; ++nt) bgq[nt] = biasg[(h * 4 + nt) * 256 + tid];

        bf16x8 aq = *reinterpret_cast<const bf16x8*>(
            &smem[LDS_XQ + q * 98 + h * 32 + lg * 8]);
        f32x4 sacc[4];
        #pragma unroll
        for (int nt = 0; nt < 4; ++nt) {
            bf16x8 bk = *reinterpret_cast<const bf16x8*>(
                &smem[LDS_K + (nt * 16 + lr) * 100 + h * 32 + lg * 8]);
            // SWAPPED: A=K, B=Q -> D[key=16nt+4lg+j][q=W+lr]
            sacc[nt] = __builtin_amdgcn_mfma_f32_16x16x32_bf16(bk, aq, (f32x4)0.f, 0, 0, 0);
        }
        // logits (lane holds 16 keys for its one query)
        float lgt[4][4];
        #pragma unroll
        for (int nt = 0; nt < 4; ++nt) {
            #pragma unroll
            for (int j = 0; j < 4; ++j) {
                int key = nt * 16 + lg * 4 + j;
                float v = -1e30f;
                if (key < 52)
                    v = sacc[nt][j] * SCALE + s2f(bgq[nt][j]) + mk[nt][j];
                lgt[nt][j] = v;
            }
        }
        // in-lane softmax + 2-shfl cross-lg reduce (lanes lr, lr+16/32/48 = same q)
        float m = lgt[0][0];
        #pragma unroll
        for (int nt = 0; nt < 4; ++nt)
            #pragma unroll
            for (int j = 0; j < 4; ++j) m = fmaxf(m, lgt[nt][j]);
        m = fmaxf(m, __shfl_xor(m, 16));
        m = fmaxf(m, __shfl_xor(m, 32));
        float p[4][4], sum = 0.f;
        #pragma unroll
        for (int nt = 0; nt < 4; ++nt)
            #pragma unroll
            for (int j = 0; j < 4; ++j) {
                p[nt][j] = __expf(lgt[nt][j] - m);
                sum += p[nt][j];
            }
        sum += __shfl_xor(sum, 16);
        sum += __shfl_xor(sum, 32);
        float inv = 1.0f / sum;
        #pragma unroll
        for (int nt = 0; nt < 4; ++nt)
            #pragma unroll
            for (int j = 0; j < 4; ++j) p[nt][j] *= inv;

        // pack P tiles: pd[nt] = 2 dwords {j0j1, j2j3}
        int pd[4][2];
        #pragma unroll
        for (int nt = 0; nt < 4; ++nt) {
            pd[nt][0] = pk2(p[nt][0], p[nt][1]);
            pd[nt][1] = pk2(p[nt][2], p[nt][3]);
        }
        // O^T += V^T . P^T : per ks build P B-frag via bpermute, 2 d-tiles
        #pragma unroll
        for (int ks = 0; ks < 2; ++ks) {
            bf16x8 pf = xfrag(pd[2 * ks][0], pd[2 * ks][1],
                              pd[2 * ks + 1][0], pd[2 * ks + 1][1], iA, iB, selHi);
            #pragma unroll
            for (int a = 0; a < 2; ++a) {
                bf16x8 vt = *reinterpret_cast<const bf16x8*>(
                    &smem[LDS_VT + (h * 32 + a * 16 + lr) * 66 + ks * 32 + lg * 8]);
                oacc[h * 2 + a] = __builtin_amdgcn_mfma_f32_16x16x32_bf16(
                    vt, pf, oacc[h * 2 + a], 0, 0, 0);
            }
        }
    }

    // ---- projection from registers: transpose O^T via bpermute, A=O B=W ----
    int od[6][2];
    #pragma unroll
    for (int T = 0; T < 6; ++T) {
        od[T][0] = pk2(oacc[T][0], oacc[T][1]);
        od[T][1] = pk2(oacc[T][2], oacc[T][3]);
    }
    f32x4 po[6];
    #pragma unroll
    for (int nt = 0; nt < 6; ++nt) po[nt] = (f32x4)0.f;
    #pragma unroll
    for (int ks = 0; ks < 3; ++ks) {
        bf16x8 of = xfrag(od[2 * ks][0], od[2 * ks][1],
                          od[2 * ks + 1][0], od[2 * ks + 1][1], iA, iB, selHi);
        #pragma unroll
        for (int nt = 0; nt < 6; ++nt) {
            bf16x8 bp = *reinterpret_cast<const bf16x8*>(
                wp + (nt * 16 + lr) * 96 + ks * 32 + lg * 8);
            po[nt] = __builtin_amdgcn_mfma_f32_16x16x32_bf16(of, bp, po[nt], 0, 0, 0);
        }
    }
    #pragma unroll
    for (int nt = 0; nt < 6; ++nt) {
        float pb = proj_b[nt * 16 + lr];
        #pragma unroll
        for (int j = 0; j < 4; ++j) {
            int n = wid * 16 + lg * 4 + j;
            if (n < 49)
                out[((size_t)w * 49 + n) * 96 + nt * 16 + lr] = po[nt][j] + pb;
        }
    }
}

// ---------------- prior highway: v_hw = proj(v(qkv(prior))) ----------------
__global__ __launch_bounds__(128)
void pawsa_prior(const float* __restrict__ uk, const float* __restrict__ fg,
                 const float* __restrict__ bg,
                 const float* __restrict__ qkv_w, const float* __restrict__ qkv_b,
                 const float* __restrict__ proj_w, const float* __restrict__ proj_b,
                 float* __restrict__ out_vhw)
{
    int blk = blockIdx.x;             // 24 = 8 batches * 3 priors
    int b = blk / 3, p = blk % 3;
    int t = threadIdx.x;
    __shared__ float prr[96], vf[96];
    const float* src = (p == 0) ? uk : (p == 1) ? fg : bg;
    if (t < 96) prr[t] = src[b * 96 + t];
    __syncthreads();
    if (t < 96) {
        float acc = qkv_b[192 + t];
        for (int k = 0; k < 96; ++k)
            acc += prr[k] * qkv_w[(192 + t) * 96 + k];
        vf[t] = acc;
    }
    __syncthreads();
    if (t < 96) {
        float acc = proj_b[t];
        for (int c = 0; c < 96; ++c)
            acc += vf[c] * proj_w[t * 96 + c];
        out_vhw[(b * 3 + p) * 96 + t] = acc;
    }
}

extern "C" void kernel_launch(void* const* d_in, const int* in_sizes, int n_in,
                              void* d_out, int out_size, void* d_ws, size_t ws_size,
                              hipStream_t stream) {
    const float* x          = (const float*)d_in[0];
    const float* mask       = (const float*)d_in[1];
    const float* uk         = (const float*)d_in[2];
    const float* fg         = (const float*)d_in[3];
    const float* bg         = (const float*)d_in[4];
    const float* qkv_w      = (const float*)d_in[5];
    const float* qkv_b      = (const float*)d_in[6];
    const float* proj_w     = (const float*)d_in[7];
    const float* proj_b     = (const float*)d_in[8];
    const float* bias_table = (const float*)d_in[9];
    float* out = (float*)d_out;
    bf16* ws   = (bf16*)d_ws;

    pawsa_prep<<<145, 256, 0, stream>>>(qkv_w, proj_w, bias_table, ws);
    pawsa_prior<<<24, 128, 0, stream>>>(uk, fg, bg, qkv_w, qkv_b, proj_w, proj_b,
                                        out + (size_t)8192 * 49 * 96);
    pawsa_main<<<8192, 256, 0, stream>>>(x, mask, uk, fg, bg,
                                         ws, qkv_b, ws + 27648, proj_b,
                                         (const u16x4*)(ws + 36864), out);
}

// Round 17
// 234.720 us; speedup vs baseline: 1.0282x; 1.0282x over previous
//
#include <hip/hip_runtime.h>
#include <hip/hip_bf16.h>

// ---------------------------------------------------------------------------
// PAWSA fused windowed attention, MI355X / gfx950 — round 17.
// Inputs f32, output f32 (out0 [8192,49,96], out1 v_hw [8,3,96] at elem
// offset 38,535,168). One block per window (8192 x 256), bf16 MFMA 16x16x32.
// = R15 (238us, zero-conflict) + two latency cuts:
//   1) XCD-aware swizzle: bid -> (b, wi) s.t. each XCD owns a contiguous
//      128-window wi chunk (1.2MB mask slice L2-resident, reused 8 batches).
//   2) Operand-swapped QKV: D=[channel][token] -> q/k scatter is one aligned
//      b64 write per mt (uniform n<49/52 predicate), bias via dwordx4.
// Attention/softmax/PV/projection byte-identical to R15.
// LDS 39,920 B -> 4 blocks/CU.
// ---------------------------------------------------------------------------

typedef __bf16 bf16x8 __attribute__((ext_vector_type(8)));
typedef float  f32x4  __attribute__((ext_vector_type(4)));
typedef short  s16x4  __attribute__((ext_vector_type(4)));
typedef unsigned short u16x4 __attribute__((ext_vector_type(4)));
using bf16 = __hip_bfloat16;

#define SCALE 0.17677669529663687f   // 32^-0.5

// LDS partition (units: 16-bit elements) — 19,960 shorts = 39,920 B
#define LDS_XQ    0       // [49][100] q (rows<49) -> O
#define LDS_K     4900    // [52][100] k
#define LDS_P     10100   // [49][68]  P (bf16 probs, per head)
#define LDS_VT    13432   // [96][68]  v^T: vt[h*32+d][token]
#define LDS_TOT   19960

static __device__ inline float s2f(unsigned short s) {
    unsigned int u = ((unsigned int)s) << 16;
    float f;
    __builtin_memcpy(&f, &u, 4);
    return f;
}
static __device__ inline short f2s(float f) {   // hardware cvt
    __bf16 h = (__bf16)f;
    short s;
    __builtin_memcpy(&s, &h, 2);
    return s;
}
static __device__ inline bf16x8 ldw8(const float* p) {   // f32 -> bf16 fragment
    f32x4 a = *reinterpret_cast<const f32x4*>(p);
    f32x4 b = *reinterpret_cast<const f32x4*>(p + 4);
    bf16x8 r;
    #pragma unroll
    for (int i = 0; i < 4; ++i) {
        r[i]     = (__bf16)a[i];
        r[i + 4] = (__bf16)b[i];
    }
    return r;
}

// ---- prep: bf16 weights (blocks 0-143) + gathered bias table (block 144) ----
// ws layout (bf16 elems): [0,27648) qkv_w | [27648,36864) proj_w |
//                         [36864, +12288) biasg as ushort4[12][256]  (R15 layout)
__global__ __launch_bounds__(256)
void pawsa_prep(const float* __restrict__ qkv_w, const float* __restrict__ proj_w,
                const float* __restrict__ bias_table, bf16* __restrict__ ws)
{
    int blk = blockIdx.x, t = threadIdx.x;
    if (blk < 144) {
        int i = blk * 256 + t;
        if (i < 27648)      ws[i] = __float2bfloat16(qkv_w[i]);
        else if (i < 36864) ws[i] = __float2bfloat16(proj_w[i - 27648]);
        return;
    }
    // biasg[(h*4+nt)*256 + t] = {bias[idx(n=wid*16+lg*4+j, c=nt*16+lr)][h]}
    int lane = t & 63, wid = t >> 6;
    int lr = lane & 15, lg = lane >> 4;
    u16x4* bg = reinterpret_cast<u16x4*>(ws + 36864);
    for (int h = 0; h < 3; ++h) {
        for (int nt = 0; nt < 4; ++nt) {
            int c = nt * 16 + lr;
            u16x4 v4;
            for (int j = 0; j < 4; ++j) {
                int n = wid * 16 + lg * 4 + j;
                int idx = 171;
                if (c < 49) {
                    idx = (n / 7 - c / 7 + 6) * 13 + ((n % 7) - (c % 7) + 6);
                    if (idx > 171 || idx < 0) idx = 171;   // garbage rows n>=49
                } else if (c < 52) {
                    idx = 169 + (c - 49);
                }
                v4[j] = (unsigned short)f2s(bias_table[idx * 3 + h]);
            }
            bg[(h * 4 + nt) * 256 + t] = v4;
        }
    }
}

__global__ __launch_bounds__(256, 4)
void pawsa_main(const float* __restrict__ x, const float* __restrict__ mask,
                const float* __restrict__ uk, const float* __restrict__ fg,
                const float* __restrict__ bg,
                const bf16* __restrict__ wq,    // bf16 qkv_w (d_ws)
                const float* __restrict__ qkv_b,
                const bf16* __restrict__ wp,    // bf16 proj_w (d_ws)
                const float* __restrict__ proj_b,
                const u16x4* __restrict__ biasg, // gathered bias (d_ws)
                float* __restrict__ out)
{
    __shared__ short smem[LDS_TOT];

    const int tid  = threadIdx.x;
    // XCD-aware swizzle: XCD x owns wi in [x*128,(x+1)*128) for all 8 batches
    const int bid  = blockIdx.x;
    const int xcd  = bid & 7;          // round-robin block->XCD assumption
    const int slot = bid >> 3;         // 0..1023
    const int wi   = xcd * 128 + (slot & 127);
    const int b    = slot >> 7;        // batch 0..7
    const int w    = b * 1024 + wi;    // window id (bijective remap)

    const int lane = tid & 63;
    const int wid  = tid >> 6;         // wave id 0..3
    const int lr   = lane & 15;        // row/col within 16-tile
    const int lg   = lane >> 4;        // k-group 0..3

    // ---- X tile -> registers directly (rows<49 x, 49-51 priors, >=52 zero) --
    bf16x8 af[3][4];
    #pragma unroll
    for (int mt = 0; mt < 4; ++mt) {
        int n = mt * 16 + lr;
        #pragma unroll
        for (int ks = 0; ks < 3; ++ks) {
            bf16x8 a = (bf16x8)0;
            if (n < 49) {
                a = ldw8(x + ((size_t)w * 49 + n) * 96 + ks * 32 + lg * 8);
            } else if (n < 52) {
                const float* pr = (n == 49) ? uk : (n == 50) ? fg : bg;
                a = ldw8(pr + b * 96 + ks * 32 + lg * 8);
            }
            af[ks][mt] = a;
        }
    }

    // ---- QKV GEMM, SWAPPED operands: D[channel][token] ----
    // wave-split tiles (0-4,5-9,10-14,13-17; 13,14 dup benign)
    const int nt0 = (wid < 3) ? wid * 5 : 13;
    #pragma unroll
    for (int i = 0; i < 5; ++i) {
        int nt = nt0 + i;
        bf16x8 bw0 = *reinterpret_cast<const bf16x8*>(wq + (nt * 16 + lr) * 96 +  0 + lg * 8);
        bf16x8 bw1 = *reinterpret_cast<const bf16x8*>(wq + (nt * 16 + lr) * 96 + 32 + lg * 8);
        bf16x8 bw2 = *reinterpret_cast<const bf16x8*>(wq + (nt * 16 + lr) * 96 + 64 + lg * 8);
        f32x4 qb4 = *reinterpret_cast<const f32x4*>(qkv_b + nt * 16 + lg * 4);
        f32x4 acc[4] = {(f32x4)0.f, (f32x4)0.f, (f32x4)0.f, (f32x4)0.f};
        #pragma unroll
        for (int mt = 0; mt < 4; ++mt) {
            // A=W (rows=channels), B=X (rows=tokens) -> D[ch=lg*4+j][tok=lr]
            acc[mt] = __builtin_amdgcn_mfma_f32_16x16x32_bf16(bw0, af[0][mt], acc[mt], 0, 0, 0);
            acc[mt] = __builtin_amdgcn_mfma_f32_16x16x32_bf16(bw1, af[1][mt], acc[mt], 0, 0, 0);
            acc[mt] = __builtin_amdgcn_mfma_f32_16x16x32_bf16(bw2, af[2][mt], acc[mt], 0, 0, 0);
        }
        int s = nt / 6;                       // 0=q 1=k 2=v (tile-uniform)
        int remBase = (nt - s * 6) * 16 + lg * 4;   // channel within q/k/v
        #pragma unroll
        for (int mt = 0; mt < 4; ++mt) {
            int n = mt * 16 + lr;             // token (uniform over j)
            if (s == 2) {                     // v^T: 4 channel-rows, col n
                #pragma unroll
                for (int j = 0; j < 4; ++j)
                    smem[LDS_VT + (remBase + j) * 68 + n] = f2s(acc[mt][j] + qb4[j]);
            } else {
                s16x4 pk;
                #pragma unroll
                for (int j = 0; j < 4; ++j) pk[j] = f2s(acc[mt][j] + qb4[j]);
                if (s == 0) { if (n < 49) *reinterpret_cast<s16x4*>(
                                  &smem[LDS_XQ + n * 100 + remBase]) = pk; }
                else        { if (n < 52) *reinterpret_cast<s16x4*>(
                                  &smem[LDS_K  + n * 100 + remBase]) = pk; }
            }
        }
    }

    // ---- mask + gathered-bias loads (af dead; hidden under barrier wait) ----
    float mk[4][4];
    #pragma unroll
    for (int nt = 0; nt < 4; ++nt) {
        int c = nt * 16 + lr;
        #pragma unroll
        for (int j = 0; j < 4; ++j) {
            int n = wid * 16 + lg * 4 + j;
            float m = 0.f;
            if (c < 49 && n < 49)
                m = mask[(size_t)wi * 2401 + n * 49 + c];
            mk[nt][j] = m;
        }
    }
    u16x4 bgv[12];
    #pragma unroll
    for (int i = 0; i < 12; ++i) bgv[i] = biasg[i * 256 + tid];

    __syncthreads();
    // From here: K, VT read-only; XQ/P rows wave-private.

    // ---- per-head attention (R15-identical; wave-private rows) ----
    #pragma unroll
    for (int h = 0; h < 3; ++h) {
        bf16x8 aq = *reinterpret_cast<const bf16x8*>(
            &smem[LDS_XQ + (wid * 16 + lr) * 100 + h * 32 + lg * 8]);
        f32x4 sacc[4];
        #pragma unroll
        for (int nt = 0; nt < 4; ++nt) {
            bf16x8 bk = *reinterpret_cast<const bf16x8*>(
                &smem[LDS_K + (nt * 16 + lr) * 100 + h * 32 + lg * 8]);
            sacc[nt] = __builtin_amdgcn_mfma_f32_16x16x32_bf16(aq, bk, (f32x4)0.f, 0, 0, 0);
        }
        float lgt[4][4];
        #pragma unroll
        for (int nt = 0; nt < 4; ++nt) {
            int c = nt * 16 + lr;
            u16x4 bgq = bgv[h * 4 + nt];
            #pragma unroll
            for (int j = 0; j < 4; ++j) {
                float v = -1e30f;
                if (c < 52)
                    v = sacc[nt][j] * SCALE + s2f(bgq[j]) + mk[nt][j];
                lgt[nt][j] = v;
            }
        }
        float pr[4][4];
        #pragma unroll
        for (int j = 0; j < 4; ++j) {
            float m = fmaxf(fmaxf(lgt[0][j], lgt[1][j]), fmaxf(lgt[2][j], lgt[3][j]));
            m = fmaxf(m, __shfl_xor(m, 1));
            m = fmaxf(m, __shfl_xor(m, 2));
            m = fmaxf(m, __shfl_xor(m, 4));
            m = fmaxf(m, __shfl_xor(m, 8));
            float sum = 0.f;
            #pragma unroll
            for (int nt = 0; nt < 4; ++nt) {
                pr[nt][j] = __expf(lgt[nt][j] - m);
                sum += pr[nt][j];
            }
            sum += __shfl_xor(sum, 1);
            sum += __shfl_xor(sum, 2);
            sum += __shfl_xor(sum, 4);
            sum += __shfl_xor(sum, 8);
            float inv = 1.0f / sum;
            #pragma unroll
            for (int nt = 0; nt < 4; ++nt) pr[nt][j] *= inv;
        }
        #pragma unroll
        for (int nt = 0; nt < 4; ++nt)
            #pragma unroll
            for (int j = 0; j < 4; ++j) {
                int prow = wid * 16 + lg * 4 + j;
                if (prow < 49)
                    smem[LDS_P + prow * 68 + nt * 16 + lr] = f2s(pr[nt][j]);
            }

        // O_h = P @ V (K=52 padded to 64; P cols 52-63 exact zeros)
        f32x4 ov[2] = {(f32x4)0.f, (f32x4)0.f};
        #pragma unroll
        for (int ks = 0; ks < 2; ++ks) {
            bf16x8 ap = *reinterpret_cast<const bf16x8*>(
                &smem[LDS_P + (wid * 16 + lr) * 68 + ks * 32 + lg * 8]);
            #pragma unroll
            for (int nt2 = 0; nt2 < 2; ++nt2) {
                bf16x8 bv = *reinterpret_cast<const bf16x8*>(
                    &smem[LDS_VT + (h * 32 + nt2 * 16 + lr) * 68 + ks * 32 + lg * 8]);
                ov[nt2] = __builtin_amdgcn_mfma_f32_16x16x32_bf16(ap, bv, ov[nt2], 0, 0, 0);
            }
        }
        #pragma unroll
        for (int nt2 = 0; nt2 < 2; ++nt2)
            #pragma unroll
            for (int j = 0; j < 4; ++j) {
                int orow = wid * 16 + lg * 4 + j;
                if (orow < 49)
                    smem[LDS_XQ + orow * 100 + h * 32 + nt2 * 16 + lr]
                        = f2s(ov[nt2][j]);
            }
    }

    // ---- projection: [64x96] @ proj_w^T[96x96] (wave-private rows) ----
    f32x4 po[6];
    #pragma unroll
    for (int nt = 0; nt < 6; ++nt) po[nt] = (f32x4)0.f;
    #pragma unroll
    for (int ks = 0; ks < 3; ++ks) {
        bf16x8 a = *reinterpret_cast<const bf16x8*>(
            &smem[LDS_XQ + (wid * 16 + lr) * 100 + ks * 32 + lg * 8]);
        #pragma unroll
        for (int nt = 0; nt < 6; ++nt) {
            bf16x8 bp = *reinterpret_cast<const bf16x8*>(
                wp + (nt * 16 + lr) * 96 + ks * 32 + lg * 8);
            po[nt] = __builtin_amdgcn_mfma_f32_16x16x32_bf16(a, bp, po[nt], 0, 0, 0);
        }
    }
    #pragma unroll
    for (int nt = 0; nt < 6; ++nt) {
        float pb = proj_b[nt * 16 + lr];
        #pragma unroll
        for (int j = 0; j < 4; ++j) {
            int n = wid * 16 + lg * 4 + j;
            if (n < 49)
                out[((size_t)w * 49 + n) * 96 + nt * 16 + lr] = po[nt][j] + pb;
        }
    }
}

// ---------------- prior highway: v_hw = proj(v(qkv(prior))) ----------------
__global__ __launch_bounds__(128)
void pawsa_prior(const float* __restrict__ uk, const float* __restrict__ fg,
                 const float* __restrict__ bg,
                 const float* __restrict__ qkv_w, const float* __restrict__ qkv_b,
                 const float* __restrict__ proj_w, const float* __restrict__ proj_b,
                 float* __restrict__ out_vhw)
{
    int blk = blockIdx.x;             // 24 = 8 batches * 3 priors
    int b = blk / 3, p = blk % 3;
    int t = threadIdx.x;
    __shared__ float prr[96], vf[96];
    const float* src = (p == 0) ? uk : (p == 1) ? fg : bg;
    if (t < 96) prr[t] = src[b * 96 + t];
    __syncthreads();
    if (t < 96) {
        float acc = qkv_b[192 + t];
        for (int k = 0; k < 96; ++k)
            acc += prr[k] * qkv_w[(192 + t) * 96 + k];
        vf[t] = acc;
    }
    __syncthreads();
    if (t < 96) {
        float acc = proj_b[t];
        for (int c = 0; c < 96; ++c)
            acc += vf[c] * proj_w[t * 96 + c];
        out_vhw[(b * 3 + p) * 96 + t] = acc;
    }
}

extern "C" void kernel_launch(void* const* d_in, const int* in_sizes, int n_in,
                              void* d_out, int out_size, void* d_ws, size_t ws_size,
                              hipStream_t stream) {
    const float* x          = (const float*)d_in[0];
    const float* mask       = (const float*)d_in[1];
    const float* uk         = (const float*)d_in[2];
    const float* fg         = (const float*)d_in[3];
    const float* bg         = (const float*)d_in[4];
    const float* qkv_w      = (const float*)d_in[5];
    const float* qkv_b      = (const float*)d_in[6];
    const float* proj_w     = (const float*)d_in[7];
    const float* proj_b     = (const float*)d_in[8];
    const float* bias_table = (const float*)d_in[9];
    float* out = (float*)d_out;
    bf16* ws   = (bf16*)d_ws;

    pawsa_prep<<<145, 256, 0, stream>>>(qkv_w, proj_w, bias_table, ws);
    pawsa_prior<<<24, 128, 0, stream>>>(uk, fg, bg, qkv_w, qkv_b, proj_w, proj_b,
                                        out + (size_t)8192 * 49 * 96);
    pawsa_main<<<8192, 256, 0, stream>>>(x, mask, uk, fg, bg,
                                         ws, qkv_b, ws + 27648, proj_b,
                                         (const u16x4*)(ws + 36864), out);
}